// Round 2
// baseline (400.832 us; speedup 1.0000x reference)
//
#include <hip/hip_runtime.h>
#include <hip/hip_bf16.h>

using bf16 = __hip_bfloat16;
typedef __attribute__((ext_vector_type(8))) short s16x8;
typedef __attribute__((ext_vector_type(4))) float f32x4;

// Read element i of a raw input tensor whose storage dtype is decided at runtime.
__device__ __forceinline__ float ldin(const void* p, size_t i, int f32) {
    return f32 ? ((const float*)p)[i] : (float)((const bf16*)p)[i];
}

// Detect storage dtype of the float tensors. Probe = Qk (values ~N(0,0.04^2)).
// Interpret 512 uint32 words; if the LOW 16 bits, viewed as bf16, ever have
// exponent >= 0xF0 (|x|>=2^97 or NaN/Inf), the data must be fp32 (random
// mantissa bits) -> flag=1. True bf16 data of this scale never triggers.
__global__ void sniff_kernel(const unsigned int* __restrict__ probe, int* __restrict__ flag) {
    __shared__ int bad;
    if (threadIdx.x == 0) bad = 0;
    __syncthreads();
    int myb = 0;
    for (int i = threadIdx.x; i < 512; i += 256) {
        unsigned int w = probe[i];
        unsigned int e = (w >> 7) & 0xFFu;   // exponent field of low-half bf16
        if (e >= 0xF0u) myb = 1;
    }
    if (myb) atomicOr(&bad, 1);
    __syncthreads();
    if (threadIdx.x == 0) *flag = bad ? 1 : 0;
}

// Stage 8 consecutive elements (row-major, element offset `off`) into LDS as bf16.
template<bool F32>
__device__ __forceinline__ void stage8(bf16* dst, const void* src, size_t off) {
    if (F32) {
        const float* g = (const float*)src + off;
        float4 f0 = *(const float4*)g;
        float4 f1 = *(const float4*)(g + 4);
        dst[0] = (bf16)f0.x; dst[1] = (bf16)f0.y; dst[2] = (bf16)f0.z; dst[3] = (bf16)f0.w;
        dst[4] = (bf16)f1.x; dst[5] = (bf16)f1.y; dst[6] = (bf16)f1.z; dst[7] = (bf16)f1.w;
    } else {
        *(uint4*)dst = *(const uint4*)((const bf16*)src + off);
    }
}

// C[M,N] = A[M,K] @ W[N,K]^T + bias[N].
// Runs only when *flagp == want (dual-instantiated per dtype mode).
// Tile: BM=64, BN=64, BK=32; 256 threads = 4 waves.
template<bool A32, bool W32, bool OUT_BF16>
__global__ __launch_bounds__(256)
void gemm_bt(const int* __restrict__ flagp, int want,
             const void* __restrict__ Ap, const void* __restrict__ Wp,
             const void* __restrict__ biasp, void* __restrict__ outp,
             int M, int N, int K) {
    if (*flagp != want) return;
    __shared__ __align__(16) bf16 lA[64 * 32];
    __shared__ __align__(16) bf16 lB[64 * 32];
    const int tid  = threadIdx.x;
    const int wave = tid >> 6;
    const int lane = tid & 63;
    const int m0 = blockIdx.x * 64;
    const int n0 = blockIdx.y * 64;
    const int srow = tid >> 2;        // 0..63
    const int scol = (tid & 3) * 8;   // 0,8,16,24
    const size_t offA = (size_t)(m0 + srow) * K + scol;
    const size_t offW = (size_t)(n0 + srow) * K + scol;
    const int quad = lane >> 4;
    const int lm   = lane & 15;
    f32x4 acc[4] = {};
    for (int k0 = 0; k0 < K; k0 += 32) {
        stage8<A32>(&lA[srow * 32 + scol], Ap, offA + k0);
        stage8<W32>(&lB[srow * 32 + scol], Wp, offW + k0);
        __syncthreads();
        s16x8 a = *(const s16x8*)(&lA[(wave * 16 + lm) * 32 + quad * 8]);
#pragma unroll
        for (int n = 0; n < 4; ++n) {
            s16x8 b = *(const s16x8*)(&lB[(n * 16 + lm) * 32 + quad * 8]);
            acc[n] = __builtin_amdgcn_mfma_f32_16x16x32_bf16(a, b, acc[n], 0, 0, 0);
        }
        __syncthreads();
    }
    // C/D layout: row = quad*4 + reg (within wave's 16 rows), col = n*16 + lm
    const int rbase = m0 + wave * 16 + quad * 4;
#pragma unroll
    for (int n = 0; n < 4; ++n) {
        int col = n0 + n * 16 + lm;
        float bv = ldin(biasp, col, W32 ? 1 : 0);
#pragma unroll
        for (int r = 0; r < 4; ++r) {
            float v = acc[n][r] + bv;
            size_t off = (size_t)(rbase + r) * N + col;
            if (OUT_BF16) ((bf16*)outp)[off] = (bf16)v;
            else          ((float*)outp)[off] = v;
        }
    }
}

// One block per (b,l) position. 256 threads.
// qp/kp fp32 (B*N,640) [internal]; vp bf16 (B*N,1792) [internal]; attn_out bf16.
// Kb/Vb/Sk/Sb are raw inputs -> read via ldin with runtime flag.
__global__ __launch_bounds__(256)
void attn_kernel(const float* __restrict__ qp, const float* __restrict__ kp,
                 const bf16* __restrict__ vp,
                 const void* __restrict__ Kb, const void* __restrict__ Vb,
                 const void* __restrict__ Sk, const void* __restrict__ Sb,
                 bf16* __restrict__ attn_out, const int* __restrict__ flagp) {
    const int f32 = *flagp;
    const int pos = blockIdx.x;           // b*1024 + l
    const int b = pos >> 10, l = pos & 1023;
    const int t = threadIdx.x;
    __shared__ float qs[640];
    __shared__ float sc5[5][32];
    __shared__ float sc14[14][32];
    __shared__ float w14[14][32];

    for (int i = t; i < 640; i += 256) qs[i] = qp[(size_t)pos * 640 + i];
    __syncthreads();

    // Phase A: banded scores per subhead: score[s][j] = dot(q[s], kwin[s][j])
    if (t < 160) {
        const int s = t >> 5, j = t & 31;
        const int dil[5] = {1, 1, 2, 4, 8};
        const int pl[5]  = {15, 15, 31, 62, 124};
        const int row = l + j * dil[s] - pl[s];
        const float* q = qs + s * 128;
        float acc = 0.f;
        if (row >= 0 && row < 1024) {
            const float* kr = kp + ((size_t)b * 1024 + row) * 640 + s * 128;
            for (int i = 0; i < 128; i += 4) {
                float4 kv = *(const float4*)(kr + i);
                acc += q[i] * kv.x + q[i + 1] * kv.y + q[i + 2] * kv.z + q[i + 3] * kv.w;
            }
        } else {
            // padded positions project the bias vector
            for (int i = 0; i < 128; ++i) acc += q[i] * ldin(Kb, s * 128 + i, f32);
        }
        sc5[s][j] = acc;
    }
    __syncthreads();

    // Phase B: supersample -> heads, positional resampling
    const int h2s[14] = {0, 0, 0, 0, 0, 1, 1, 1, 1, 1, 2, 2, 3, 4};
    for (int idx = t; idx < 448; idx += 256) {
        const int h = idx >> 5, j2 = idx & 31;
        const int s = h2s[h];
        float acc = ldin(Sb, h * 32 + j2, f32);
        const size_t skbase = ((size_t)h * 32 + j2) * 32;
        for (int k = 0; k < 32; ++k) acc += sc5[s][k] * ldin(Sk, skbase + k, f32);
        sc14[h][j2] = acc;
    }
    __syncthreads();

    // Phase C: softmax over j (32) per head
    if (t < 14) {
        float mx = -1e30f;
        for (int j = 0; j < 32; ++j) mx = fmaxf(mx, sc14[t][j]);
        float sum = 0.f;
        for (int j = 0; j < 32; ++j) { float e = __expf(sc14[t][j] - mx); w14[t][j] = e; sum += e; }
        float inv = 1.f / sum;
        for (int j = 0; j < 32; ++j) w14[t][j] *= inv;
    }
    __syncthreads();

    // Phase D: attn[h][d] = sum_j w[h][j] * vwin[h][j][d]
    const int dilh[14] = {1, 1, 1, 1, 1, 1, 1, 1, 1, 1, 2, 2, 4, 8};
    const int plh[14]  = {15, 15, 15, 15, 15, 15, 15, 15, 15, 15, 31, 31, 62, 124};
    for (int idx = t; idx < 1792; idx += 256) {
        const int h = idx >> 7;
        const int dd = dilh[h], pp = plh[h];
        float acc = 0.f;
        for (int j = 0; j < 32; ++j) {
            const int row = l + j * dd - pp;
            float v = (row >= 0 && row < 1024)
                          ? (float)vp[((size_t)b * 1024 + row) * 1792 + idx]
                          : ldin(Vb, idx, f32);   // padded positions project the bias vector
            acc += w14[h][j] * v;
        }
        attn_out[(size_t)pos * 1792 + idx] = (bf16)acc;
    }
}

extern "C" void kernel_launch(void* const* d_in, const int* in_sizes, int n_in,
                              void* d_out, int out_size, void* d_ws, size_t ws_size,
                              hipStream_t stream) {
    const void* query = d_in[0];
    const void* key   = d_in[1];
    const void* value = d_in[2];
    const void* Qk = d_in[3];
    const void* Qb = d_in[4];
    const void* Kk = d_in[5];
    const void* Kb = d_in[6];
    const void* Vk = d_in[7];
    const void* Vb = d_in[8];
    const void* Sk = d_in[9];
    const void* Sb = d_in[10];
    const void* Ck = d_in[11];
    const void* Cb = d_in[12];

    const int M = 2048;  // B*N
    // workspace layout: [flag(16B pad)] [qp f32 2048*640] [kp f32 2048*640]
    //                   [vp bf16 2048*1792] [atn bf16 2048*1792]   => ~25.2 MB
    int*   flagp = (int*)d_ws;
    float* qp  = (float*)((char*)d_ws + 16);
    float* kp  = qp + (size_t)M * 640;
    bf16*  vp  = (bf16*)(kp + (size_t)M * 640);
    bf16*  atn = vp + (size_t)M * 1792;

    dim3 blk(256);
    sniff_kernel<<<dim3(1), blk, 0, stream>>>((const unsigned int*)Qk, flagp);

    // bf16-storage variants (run iff flag==0)
    gemm_bt<false, false, false><<<dim3(32, 10), blk, 0, stream>>>(flagp, 0, query, Qk, Qb, qp,  M, 640, 640);
    gemm_bt<false, false, false><<<dim3(32, 10), blk, 0, stream>>>(flagp, 0, key,   Kk, Kb, kp,  M, 640, 640);
    gemm_bt<false, false, true ><<<dim3(32, 28), blk, 0, stream>>>(flagp, 0, value, Vk, Vb, vp,  M, 1792, 640);
    // fp32-storage variants (run iff flag==1)
    gemm_bt<true,  true,  false><<<dim3(32, 10), blk, 0, stream>>>(flagp, 1, query, Qk, Qb, qp,  M, 640, 640);
    gemm_bt<true,  true,  false><<<dim3(32, 10), blk, 0, stream>>>(flagp, 1, key,   Kk, Kb, kp,  M, 640, 640);
    gemm_bt<true,  true,  true ><<<dim3(32, 28), blk, 0, stream>>>(flagp, 1, value, Vk, Vb, vp,  M, 1792, 640);

    attn_kernel<<<dim3(2048), blk, 0, stream>>>(qp, kp, vp, Kb, Vb, Sk, Sb, atn, flagp);

    // collapse: A = atn (always bf16 internal); W/bias/out follow storage mode
    gemm_bt<false, false, true ><<<dim3(32, 10), blk, 0, stream>>>(flagp, 0, atn, Ck, Cb, d_out, M, 640, 1792);
    gemm_bt<false, true,  false><<<dim3(32, 10), blk, 0, stream>>>(flagp, 1, atn, Ck, Cb, d_out, M, 640, 1792);
}

// Round 3
// 183.147 us; speedup vs baseline: 2.1886x; 2.1886x over previous
//
#include <hip/hip_runtime.h>
#include <hip/hip_bf16.h>

using bf16 = __hip_bfloat16;
typedef __attribute__((ext_vector_type(8))) short s16x8;
typedef __attribute__((ext_vector_type(4))) float f32x4;
typedef unsigned int u32;

__device__ __forceinline__ float b2f(short u) {
    union { float f; u32 i; } x; x.i = ((u32)(unsigned short)u) << 16; return x.f;
}
__device__ __forceinline__ short f2b(float f) {
    bf16 h = (bf16)f; return *(short*)&h;
}

// async global->LDS 16B DMA. Per-wave: LDS dst must be wave-uniform base + lane*16.
__device__ __forceinline__ void glds16(const bf16* g, bf16* l) {
#if __has_builtin(__builtin_amdgcn_global_load_lds)
    __builtin_amdgcn_global_load_lds(
        (const __attribute__((address_space(1))) u32*)g,
        (__attribute__((address_space(3))) u32*)l, 16, 0, 0);
#else
    *(uint4*)l = *(const uint4*)g;
#endif
}

// ---- dtype sniff: fp32 vs bf16 storage (probe = Qk, values ~N(0,0.04^2)) ----
__global__ void sniff_kernel(const u32* __restrict__ probe, int* __restrict__ flag) {
    __shared__ int bad;
    if (threadIdx.x == 0) bad = 0;
    __syncthreads();
    int myb = 0;
    for (int i = threadIdx.x; i < 512; i += 256) {
        u32 e = (probe[i] >> 7) & 0xFFu;   // exponent of low-half-as-bf16
        if (e >= 0xF0u) myb = 1;           // impossible for real bf16 at this scale
    }
    if (myb) atomicOr(&bad, 1);
    __syncthreads();
    if (threadIdx.x == 0) *flag = bad ? 1 : 0;
}

// ---- normalize all 13 inputs to bf16 in ws ----
struct CvtArgs {
    const void* src[13];
    bf16* dst[13];
    int n[13];
    int bb[14];   // cumulative block bases
};
__global__ __launch_bounds__(256)
void convert_kernel(CvtArgs a, const int* __restrict__ flagp) {
    const int f32 = *flagp;
    const int blk = blockIdx.x;
    int s = 0;
    while (s < 12 && blk >= a.bb[s + 1]) ++s;
    const int base = (blk - a.bb[s]) * 1024 + threadIdx.x * 4;
    if (base >= a.n[s]) return;            // n % 4 == 0 for every tensor
    bf16* dst = a.dst[s] + base;
    if (f32) {
        float4 v = *((const float4*)a.src[s] + (base >> 2));
        dst[0] = (bf16)v.x; dst[1] = (bf16)v.y; dst[2] = (bf16)v.z; dst[3] = (bf16)v.w;
    } else {
        *(ushort4*)dst = *((const ushort4*)a.src[s] + (base >> 2));
    }
}

// ---- GEMM: C[M,N] = A[M,K] @ W[N,K]^T + bias ----
// BM x BN tile, BK=32, 256 threads = 4 waves in 2x2; glds 16B staging.
// OUT: 0 = fp32, 1 = bf16, 2 = runtime (*flagp ? fp32 : bf16).
// blockIdx.z selects pointer set (fused Q/K projection).
template<int BM, int BN, int OUT>
__global__ __launch_bounds__(256)
void gemm_v2(const bf16* __restrict__ A0, const bf16* __restrict__ W0,
             const bf16* __restrict__ b0, void* __restrict__ o0,
             const bf16* __restrict__ A1, const bf16* __restrict__ W1,
             const bf16* __restrict__ b1, void* __restrict__ o1,
             int M, int N, int K, const int* __restrict__ flagp) {
    const bf16* A    = blockIdx.z ? A1 : A0;
    const bf16* W    = blockIdx.z ? W1 : W0;
    const bf16* bias = blockIdx.z ? b1 : b0;
    void*       out  = blockIdx.z ? o1 : o0;
    constexpr int WM = BM / 2, WN = BN / 2, FM = WM / 16, FN = WN / 16;
    constexpr int SA = (BM * 4) / 256, SB = (BN * 4) / 256;  // 16B slots per thread
    __shared__ __align__(16) bf16 lA[BM * 32];
    __shared__ __align__(16) bf16 lB[BN * 32];
    const int tid = threadIdx.x;
    const int wave = tid >> 6, lane = tid & 63;
    const int wr = wave >> 1, wc = wave & 1;
    const int quad = lane >> 4, lm = lane & 15;
    const int m0 = blockIdx.x * BM, n0 = blockIdx.y * BN;
    f32x4 acc[FM][FN] = {};
    for (int k0 = 0; k0 < K; k0 += 32) {
#pragma unroll
        for (int q = 0; q < SA; ++q) {
            int sl = q * 256 + tid;        // lane-contiguous per wave
            glds16(A + (size_t)(m0 + (sl >> 2)) * K + k0 + (sl & 3) * 8, lA + sl * 8);
        }
#pragma unroll
        for (int q = 0; q < SB; ++q) {
            int sl = q * 256 + tid;
            glds16(W + (size_t)(n0 + (sl >> 2)) * K + k0 + (sl & 3) * 8, lB + sl * 8);
        }
        __syncthreads();
        s16x8 afr[FM], bfr[FN];
#pragma unroll
        for (int i = 0; i < FM; ++i)
            afr[i] = *(const s16x8*)&lA[(wr * WM + i * 16 + lm) * 32 + quad * 8];
#pragma unroll
        for (int j = 0; j < FN; ++j)
            bfr[j] = *(const s16x8*)&lB[(wc * WN + j * 16 + lm) * 32 + quad * 8];
#pragma unroll
        for (int i = 0; i < FM; ++i)
#pragma unroll
            for (int j = 0; j < FN; ++j)
                acc[i][j] = __builtin_amdgcn_mfma_f32_16x16x32_bf16(afr[i], bfr[j], acc[i][j], 0, 0, 0);
        __syncthreads();
    }
    const int f32out = (OUT == 0) ? 1 : (OUT == 1) ? 0 : *flagp;
#pragma unroll
    for (int i = 0; i < FM; ++i) {
        const int rbase = m0 + wr * WM + i * 16 + quad * 4;
#pragma unroll
        for (int j = 0; j < FN; ++j) {
            const int col = n0 + wc * WN + j * 16 + lm;
            const float bv = (float)bias[col];
#pragma unroll
            for (int r = 0; r < 4; ++r) {
                float v = acc[i][j][r] + bv;
                size_t off = (size_t)(rbase + r) * N + col;
                if (f32out) ((float*)out)[off] = v;
                else        ((bf16*)out)[off] = (bf16)v;
            }
        }
    }
}

// ---- attention core: one block per position ----
// qp/kp fp32 [2048][640]; vp bf16 [2048][1792]; atn bf16 [2048][1792].
__global__ __launch_bounds__(256)
void attn_v2(const float* __restrict__ qp, const float* __restrict__ kp,
             const bf16* __restrict__ vp,
             const bf16* __restrict__ Kbc, const bf16* __restrict__ Vbc,
             const bf16* __restrict__ Skc, const bf16* __restrict__ Sbc,
             bf16* __restrict__ atn) {
    const int pos = blockIdx.x, b = pos >> 10, l = pos & 1023;
    const int t = threadIdx.x;
    __shared__ float qs[640];
    __shared__ float partA[5 * 256];
    __shared__ float sc5[5 * 32];
    __shared__ float sc14[14 * 32];
    __shared__ float w14[14 * 32];

    for (int i = t; i < 640; i += 256) qs[i] = qp[(size_t)pos * 640 + i];
    __syncthreads();

    // Phase A: score[s][j] = q[s] . kwin[s][j]; 8 threads per dot (16 cols each)
    {
        const int j = t >> 3, part = t & 7, cbase = part * 16;
#pragma unroll
        for (int s = 0; s < 5; ++s) {
            const int dil = (s < 2) ? 1 : (1 << (s - 1));
            const int pl = (31 * dil) >> 1;
            const int row = l + j * dil - pl;
            const float* q = qs + s * 128 + cbase;
            float acc = 0.f;
            if (row >= 0 && row < 1024) {
                const float* kr = kp + (size_t)((b << 10) | row) * 640 + s * 128 + cbase;
#pragma unroll
                for (int c = 0; c < 16; c += 4) {
                    float4 kv = *(const float4*)(kr + c);
                    acc += q[c] * kv.x + q[c + 1] * kv.y + q[c + 2] * kv.z + q[c + 3] * kv.w;
                }
            } else {
                const bf16* kb = Kbc + s * 128 + cbase;  // pad rows project the bias
#pragma unroll
                for (int c = 0; c < 16; ++c) acc += q[c] * (float)kb[c];
            }
            partA[s * 256 + t] = acc;
        }
    }
    __syncthreads();
    if (t < 160) {
        const int s = t >> 5, j = t & 31;
        const float* p = partA + s * 256 + j * 8;
        sc5[s * 32 + j] = ((p[0] + p[1]) + (p[2] + p[3])) + ((p[4] + p[5]) + (p[6] + p[7]));
    }
    __syncthreads();

    // Phase B: supersample + positional resampling (448 outputs)
    {
        int idx = t;
#pragma unroll
        for (int rep = 0; rep < 2; ++rep, idx += 256) {
            if (idx < 448) {
                const int h = idx >> 5;
                const int s = (h < 5) ? 0 : (h < 10) ? 1 : (h < 12) ? 2 : (h == 12) ? 3 : 4;
                float acc = b2f(((const short*)Sbc)[idx]);
                const short* sk = (const short*)Skc + idx * 32;
                const float* sc = sc5 + s * 32;
#pragma unroll
                for (int k = 0; k < 32; ++k) acc += sc[k] * b2f(sk[k]);
                sc14[idx] = acc;
            }
        }
    }
    __syncthreads();

    // Phase C: softmax over 32 per head
    if (t < 14) {
        const float* srow = sc14 + t * 32;
        float* wrow = w14 + t * 32;
        float mx = srow[0];
        for (int j = 1; j < 32; ++j) mx = fmaxf(mx, srow[j]);
        float sum = 0.f;
        for (int j = 0; j < 32; ++j) { float e = __expf(srow[j] - mx); wrow[j] = e; sum += e; }
        float inv = 1.f / sum;
        for (int j = 0; j < 32; ++j) wrow[j] *= inv;
    }
    __syncthreads();

    // Phase D: attn[h][d] = sum_j w[h][j] * vwin[h][j][d]; one thread per (h, d8)
    if (t < 224) {
        const int h = t >> 4, d8 = (t & 15) * 8;
        const int dil = (h < 10) ? 1 : (h < 12) ? 2 : (h == 12) ? 4 : 8;
        const int pl = (31 * dil) >> 1;
        const int col = h * 128 + d8;
        const float* wrow = w14 + h * 32;
        float acc[8] = {};
#pragma unroll
        for (int j = 0; j < 32; ++j) {
            const int row = l + j * dil - pl;
            const short* src = (row >= 0 && row < 1024)
                ? (const short*)vp + (size_t)((b << 10) | row) * 1792 + col
                : (const short*)Vbc + col;     // pad rows project the bias
            s16x8 v8 = *(const s16x8*)src;
            const float w = wrow[j];
#pragma unroll
            for (int r = 0; r < 8; ++r) acc[r] += w * b2f(v8[r]);
        }
        union { uint4 u; short h16[8]; } o;
#pragma unroll
        for (int r = 0; r < 8; ++r) o.h16[r] = f2b(acc[r]);
        *(uint4*)((short*)atn + (size_t)pos * 1792 + col) = o.u;
    }
}

extern "C" void kernel_launch(void* const* d_in, const int* in_sizes, int n_in,
                              void* d_out, int out_size, void* d_ws, size_t ws_size,
                              hipStream_t stream) {
    const int M = 2048;
    char* w = (char*)d_ws;
    size_t off = 0;
    auto alloc = [&](size_t bytes) -> char* {
        off = (off + 255) & ~(size_t)255;
        char* p = w + off; off += bytes; return p;
    };
    int*  flagp = (int*)alloc(4);
    bf16* qc  = (bf16*)alloc((size_t)M * 640 * 2);     // aliased by atn later
    bf16* kc  = (bf16*)alloc((size_t)M * 640 * 2);
    bf16* vc  = (bf16*)alloc((size_t)M * 640 * 2);
    bf16* Qkc = (bf16*)alloc(409600 * 2);
    bf16* Kkc = (bf16*)alloc(409600 * 2);
    bf16* Vkc = (bf16*)alloc(1146880 * 2);
    bf16* Ckc = (bf16*)alloc(1146880 * 2);
    bf16* Qbc = (bf16*)alloc(640 * 2);
    bf16* Kbc = (bf16*)alloc(640 * 2);
    bf16* Vbc = (bf16*)alloc(1792 * 2);
    bf16* Skc = (bf16*)alloc(14336 * 2);
    bf16* Sbc = (bf16*)alloc(448 * 2);
    bf16* Cbc = (bf16*)alloc(640 * 2);
    float* qp = (float*)alloc((size_t)M * 640 * 4);
    float* kp = (float*)alloc((size_t)M * 640 * 4);
    bf16*  vp = (bf16*)alloc((size_t)M * 1792 * 2);
    bf16*  atn = qc;   // alias: qc/kc/vc are fully consumed before attn writes atn

    dim3 blk(256);
    sniff_kernel<<<dim3(1), blk, 0, stream>>>((const u32*)d_in[3], flagp);

    CvtArgs ca;
    const int srcIdx[13] = {0, 1, 2, 3, 4, 5, 6, 7, 8, 9, 10, 11, 12};
    bf16* dsts[13] = {qc, kc, vc, Qkc, Qbc, Kkc, Kbc, Vkc, Vbc, Skc, Sbc, Ckc, Cbc};
    const int ns[13] = {1310720, 1310720, 1310720, 409600, 640, 409600, 640,
                        1146880, 1792, 14336, 448, 1146880, 640};
    int cum = 0;
    for (int i = 0; i < 13; ++i) {
        ca.src[i] = d_in[srcIdx[i]];
        ca.dst[i] = dsts[i];
        ca.n[i] = ns[i];
        ca.bb[i] = cum;
        cum += (ns[i] + 1023) / 1024;
    }
    ca.bb[13] = cum;
    convert_kernel<<<dim3(cum), blk, 0, stream>>>(ca, flagp);

    // fused Q/K projection (z selects), fp32 out
    gemm_v2<64, 64, 0><<<dim3(32, 10, 2), blk, 0, stream>>>(
        qc, Qkc, Qbc, qp, kc, Kkc, Kbc, kp, M, 640, 640, flagp);
    // V projection, bf16 out
    gemm_v2<64, 64, 1><<<dim3(32, 28, 1), blk, 0, stream>>>(
        vc, Vkc, Vbc, vp, vc, Vkc, Vbc, vp, M, 1792, 640, flagp);
    // attention core
    attn_v2<<<dim3(2048), blk, 0, stream>>>(qp, kp, vp, Kbc, Vbc, Skc, Sbc, atn);
    // collapse, out dtype follows input storage
    gemm_v2<64, 64, 2><<<dim3(32, 10, 1), blk, 0, stream>>>(
        atn, Ckc, Cbc, d_out, atn, Ckc, Cbc, d_out, M, 640, 1792, flagp);
}

// Round 4
// 183.094 us; speedup vs baseline: 2.1892x; 1.0003x over previous
//
#include <hip/hip_runtime.h>
#include <hip/hip_bf16.h>

using bf16 = __hip_bfloat16;
typedef __attribute__((ext_vector_type(8))) short s16x8;
typedef __attribute__((ext_vector_type(4))) float f32x4;
typedef unsigned int u32;

__device__ __forceinline__ float b2f(short u) {
    union { float f; u32 i; } x; x.i = ((u32)(unsigned short)u) << 16; return x.f;
}
__device__ __forceinline__ short f2b(float f) {
    bf16 h = (bf16)f; return *(short*)&h;
}

// async global->LDS 16B DMA (wave-uniform base + lane*16 pattern)
__device__ __forceinline__ void glds16(const bf16* g, bf16* l) {
#if __has_builtin(__builtin_amdgcn_global_load_lds)
    __builtin_amdgcn_global_load_lds(
        (const __attribute__((address_space(1))) u32*)g,
        (__attribute__((address_space(3))) u32*)l, 16, 0, 0);
#else
    *(uint4*)l = *(const uint4*)g;
#endif
}

// ---- convert weight tensors fp32 -> bf16 (10 tensors) ----
struct CvtArgs { const float* src[10]; bf16* dst[10]; int n[10]; int bb[11]; };
__global__ __launch_bounds__(256)
void convert_kernel(CvtArgs a) {
    const int blk = blockIdx.x;
    int s = 0;
    while (s < 9 && blk >= a.bb[s + 1]) ++s;
    const int base = (blk - a.bb[s]) * 1024 + threadIdx.x * 4;
    if (base >= a.n[s]) return;            // all n % 4 == 0
    float4 v = *(const float4*)(a.src[s] + base);
    ushort4 o;
    o.x = (unsigned short)f2b(v.x); o.y = (unsigned short)f2b(v.y);
    o.z = (unsigned short)f2b(v.z); o.w = (unsigned short)f2b(v.w);
    *(ushort4*)(a.dst[s] + base) = o;
}

// ---- 64x64 GEMM tile core: C[M,N] = A[M,K] @ W[N,K]^T + bias ----
// A row stride == K. A either fp32 (convert-on-stage) or bf16 (glds16).
template<bool A_F32, bool OUT_F32>
__device__ __forceinline__ void gemm64(
    const void* __restrict__ A, const bf16* __restrict__ W,
    const bf16* __restrict__ bias, void* __restrict__ out,
    int m0, int n0, int N, int K, bf16* lA, bf16* lB) {
    const int tid = threadIdx.x;
    const int wave = tid >> 6, lane = tid & 63;
    const int wr = wave >> 1, wc = wave & 1;
    const int quad = lane >> 4, lm = lane & 15;
    const int srow = tid >> 2, scol8 = (tid & 3) * 8;  // srow*32+scol8 == tid*8
    f32x4 acc[2][2] = {};
    for (int k0 = 0; k0 < K; k0 += 32) {
        if (A_F32) {
            const float* g = (const float*)A + (size_t)(m0 + srow) * K + k0 + scol8;
            float4 f0 = *(const float4*)g;
            float4 f1 = *(const float4*)(g + 4);
            union { uint4 u; short h[8]; } p;
            p.h[0] = f2b(f0.x); p.h[1] = f2b(f0.y); p.h[2] = f2b(f0.z); p.h[3] = f2b(f0.w);
            p.h[4] = f2b(f1.x); p.h[5] = f2b(f1.y); p.h[6] = f2b(f1.z); p.h[7] = f2b(f1.w);
            *(uint4*)(lA + tid * 8) = p.u;
        } else {
            glds16((const bf16*)A + (size_t)(m0 + srow) * K + k0 + scol8, lA + tid * 8);
        }
        glds16(W + (size_t)(n0 + srow) * K + k0 + scol8, lB + tid * 8);
        __syncthreads();
        s16x8 af[2], bf[2];
#pragma unroll
        for (int i = 0; i < 2; ++i)
            af[i] = *(const s16x8*)&lA[(wr * 32 + i * 16 + lm) * 32 + quad * 8];
#pragma unroll
        for (int j = 0; j < 2; ++j)
            bf[j] = *(const s16x8*)&lB[(wc * 32 + j * 16 + lm) * 32 + quad * 8];
#pragma unroll
        for (int i = 0; i < 2; ++i)
#pragma unroll
            for (int j = 0; j < 2; ++j)
                acc[i][j] = __builtin_amdgcn_mfma_f32_16x16x32_bf16(af[i], bf[j], acc[i][j], 0, 0, 0);
        __syncthreads();
    }
#pragma unroll
    for (int i = 0; i < 2; ++i) {
        const int rbase = m0 + wr * 32 + i * 16 + quad * 4;
#pragma unroll
        for (int j = 0; j < 2; ++j) {
            const int col = n0 + wc * 32 + j * 16 + lm;
            const float bv = (float)bias[col];
#pragma unroll
            for (int r = 0; r < 4; ++r) {
                float v = acc[i][j][r] + bv;
                size_t off = (size_t)(rbase + r) * N + col;
                if (OUT_F32) ((float*)out)[off] = v;
                else         ((bf16*)out)[off] = (bf16)v;
            }
        }
    }
}

// ---- fused Q/K/V projection, XCD-swizzled 1-D grid of 32*48=1536 blocks ----
// per XCD: 4 m-tiles x 48 n-tiles (10 Q + 10 K + 28 V)
__global__ __launch_bounds__(256)
void proj_kernel(const float* __restrict__ q, const float* __restrict__ k,
                 const float* __restrict__ v,
                 const bf16* __restrict__ Qkc, const bf16* __restrict__ Kkc,
                 const bf16* __restrict__ Vkc,
                 const bf16* __restrict__ Qbc, const bf16* __restrict__ Kbc,
                 const bf16* __restrict__ Vbc,
                 float* __restrict__ qp, float* __restrict__ kp,
                 bf16* __restrict__ vp) {
    __shared__ __align__(16) bf16 lA[64 * 32];
    __shared__ __align__(16) bf16 lB[64 * 32];
    const int L = blockIdx.x, xcd = L & 7, i = L >> 3;
    const int m0 = (xcd * 4 + i / 48) * 64;
    const int nid = i % 48;
    if (nid < 10)
        gemm64<true, true >(q, Qkc, Qbc, qp, m0, nid * 64, 640, 640, lA, lB);
    else if (nid < 20)
        gemm64<true, true >(k, Kkc, Kbc, kp, m0, (nid - 10) * 64, 640, 640, lA, lB);
    else
        gemm64<true, false>(v, Vkc, Vbc, vp, m0, (nid - 20) * 64, 1792, 640, lA, lB);
}

// ---- collapse GEMM: out[2048,640] = atn[2048,1792] @ Ck[640,1792]^T + Cb ----
__global__ __launch_bounds__(256)
void collapse_kernel(const bf16* __restrict__ atn, const bf16* __restrict__ Ckc,
                     const bf16* __restrict__ Cbc, float* __restrict__ out) {
    __shared__ __align__(16) bf16 lA[64 * 32];
    __shared__ __align__(16) bf16 lB[64 * 32];
    const int L = blockIdx.x, xcd = L & 7, i = L >> 3;
    const int m0 = (xcd * 4 + i / 10) * 64;
    const int n0 = (i % 10) * 64;
    gemm64<false, true>(atn, Ckc, Cbc, out, m0, n0, 640, 1792, lA, lB);
}

// ---- attention core: one block per position, XCD-swizzled ----
__global__ __launch_bounds__(256)
void attn_v3(const float* __restrict__ qp, const float* __restrict__ kp,
             const bf16* __restrict__ vp,
             const bf16* __restrict__ Kbc, const bf16* __restrict__ Vbc,
             const bf16* __restrict__ Skc, const bf16* __restrict__ Sbc,
             bf16* __restrict__ atn) {
    const int pos = ((blockIdx.x & 7) << 8) | (blockIdx.x >> 3);  // XCD-contiguous
    const int b = pos >> 10, l = pos & 1023;
    const int t = threadIdx.x;
    __shared__ float qs[640];
    __shared__ float partA[5 * 256];
    __shared__ float sc5[5 * 32];
    __shared__ float sc14[14 * 32];
    __shared__ float w14[14 * 32];

    for (int i = t; i < 640; i += 256) qs[i] = qp[(size_t)pos * 640 + i];
    __syncthreads();

    // Phase A: score[s][j] = q[s] . kwin[s][j]; 8 threads per dot
    {
        const int j = t >> 3, cbase = (t & 7) * 16;
#pragma unroll
        for (int s = 0; s < 5; ++s) {
            const int dil = (s < 2) ? 1 : (1 << (s - 1));
            const int pl = (31 * dil) >> 1;
            const int row = l + j * dil - pl;
            const float* q = qs + s * 128 + cbase;
            float acc = 0.f;
            if (row >= 0 && row < 1024) {
                const float* kr = kp + (size_t)((b << 10) | row) * 640 + s * 128 + cbase;
#pragma unroll
                for (int c = 0; c < 16; c += 4) {
                    float4 kv = *(const float4*)(kr + c);
                    acc += q[c] * kv.x + q[c + 1] * kv.y + q[c + 2] * kv.z + q[c + 3] * kv.w;
                }
            } else {
                const bf16* kb = Kbc + s * 128 + cbase;  // pad rows project the bias
#pragma unroll
                for (int c = 0; c < 16; ++c) acc += q[c] * (float)kb[c];
            }
            partA[s * 256 + t] = acc;
        }
    }
    __syncthreads();
    if (t < 160) {
        const int s = t >> 5, j = t & 31;
        const float* p = partA + s * 256 + j * 8;
        sc5[s * 32 + j] = ((p[0] + p[1]) + (p[2] + p[3])) + ((p[4] + p[5]) + (p[6] + p[7]));
    }
    __syncthreads();

    // Phase B: supersample + positional resampling (448 outputs), vectorized Sk
    for (int idx = t; idx < 448; idx += 256) {
        const int h = idx >> 5;
        const int s = (h < 5) ? 0 : (h < 10) ? 1 : (h < 12) ? 2 : (h == 12) ? 3 : 4;
        const s16x8* sk = (const s16x8*)((const short*)Skc + idx * 32);
        const float* sc = sc5 + s * 32;
        float acc = b2f(((const short*)Sbc)[idx]);
#pragma unroll
        for (int g = 0; g < 4; ++g) {
            s16x8 kk = sk[g];
#pragma unroll
            for (int r = 0; r < 8; ++r) acc += sc[g * 8 + r] * b2f(kk[r]);
        }
        sc14[idx] = acc;
    }
    __syncthreads();

    // Phase C: softmax over 32 per head
    if (t < 14) {
        const float* srow = sc14 + t * 32;
        float* wrow = w14 + t * 32;
        float mx = srow[0];
        for (int j = 1; j < 32; ++j) mx = fmaxf(mx, srow[j]);
        float sum = 0.f;
        for (int j = 0; j < 32; ++j) { float e = __expf(srow[j] - mx); wrow[j] = e; sum += e; }
        float inv = 1.f / sum;
        for (int j = 0; j < 32; ++j) wrow[j] *= inv;
    }
    __syncthreads();

    // Phase D: attn[h][d] = sum_j w[h][j] * vwin[h][j][d]; one thread per (h, d8)
    if (t < 224) {
        const int h = t >> 4, d8 = (t & 15) * 8;
        const int dil = (h < 10) ? 1 : (h < 12) ? 2 : (h == 12) ? 4 : 8;
        const int pl = (31 * dil) >> 1;
        const int col = h * 128 + d8;
        const float* wrow = w14 + h * 32;
        float acc[8] = {};
#pragma unroll
        for (int j = 0; j < 32; ++j) {
            const int row = l + j * dil - pl;
            const short* src = (row >= 0 && row < 1024)
                ? (const short*)vp + (size_t)((b << 10) | row) * 1792 + col
                : (const short*)Vbc + col;     // pad rows project the bias
            s16x8 v8 = *(const s16x8*)src;
            const float w = wrow[j];
#pragma unroll
            for (int r = 0; r < 8; ++r) acc[r] += w * b2f(v8[r]);
        }
        union { uint4 u; short h16[8]; } o;
#pragma unroll
        for (int r = 0; r < 8; ++r) o.h16[r] = f2b(acc[r]);
        *(uint4*)((short*)atn + (size_t)pos * 1792 + col) = o.u;
    }
}

extern "C" void kernel_launch(void* const* d_in, const int* in_sizes, int n_in,
                              void* d_out, int out_size, void* d_ws, size_t ws_size,
                              hipStream_t stream) {
    const int M = 2048;
    char* w = (char*)d_ws;
    size_t off = 0;
    auto alloc = [&](size_t bytes) -> char* {
        off = (off + 255) & ~(size_t)255;
        char* p = w + off; off += bytes; return p;
    };
    bf16* Qkc = (bf16*)alloc(409600 * 2);
    bf16* Qbc = (bf16*)alloc(640 * 2);
    bf16* Kkc = (bf16*)alloc(409600 * 2);
    bf16* Kbc = (bf16*)alloc(640 * 2);
    bf16* Vkc = (bf16*)alloc(1146880 * 2);
    bf16* Vbc = (bf16*)alloc(1792 * 2);
    bf16* Skc = (bf16*)alloc(14336 * 2);
    bf16* Sbc = (bf16*)alloc(448 * 2);
    bf16* Ckc = (bf16*)alloc(1146880 * 2);
    bf16* Cbc = (bf16*)alloc(640 * 2);
    float* qp = (float*)alloc((size_t)M * 640 * 4);
    float* kp = (float*)alloc((size_t)M * 640 * 4);
    bf16*  vp = (bf16*)alloc((size_t)M * 1792 * 2);
    bf16*  atn = (bf16*)alloc((size_t)M * 1792 * 2);

    // convert weights (d_in idx 3..12) fp32 -> bf16
    CvtArgs ca;
    bf16* dsts[10] = {Qkc, Qbc, Kkc, Kbc, Vkc, Vbc, Skc, Sbc, Ckc, Cbc};
    const int ns[10] = {409600, 640, 409600, 640, 1146880, 1792, 14336, 448, 1146880, 640};
    int cum = 0;
    for (int i = 0; i < 10; ++i) {
        ca.src[i] = (const float*)d_in[3 + i];
        ca.dst[i] = dsts[i];
        ca.n[i] = ns[i];
        ca.bb[i] = cum;
        cum += (ns[i] + 1023) / 1024;
    }
    ca.bb[10] = cum;

    dim3 blk(256);
    convert_kernel<<<dim3(cum), blk, 0, stream>>>(ca);
    proj_kernel<<<dim3(32 * 48), blk, 0, stream>>>(
        (const float*)d_in[0], (const float*)d_in[1], (const float*)d_in[2],
        Qkc, Kkc, Vkc, Qbc, Kbc, Vbc, qp, kp, vp);
    attn_v3<<<dim3(2048), blk, 0, stream>>>(qp, kp, vp, Kbc, Vbc, Skc, Sbc, atn);
    collapse_kernel<<<dim3(320), blk, 0, stream>>>(atn, Ckc, Cbc, (float*)d_out);
}

// Round 5
// 171.586 us; speedup vs baseline: 2.3360x; 1.0671x over previous
//
#include <hip/hip_runtime.h>
#include <hip/hip_bf16.h>

using bf16 = __hip_bfloat16;
typedef __attribute__((ext_vector_type(8))) short s16x8;
typedef __attribute__((ext_vector_type(4))) float f32x4;
typedef unsigned int u32;

__device__ __forceinline__ float b2f(short u) {
    union { float f; u32 i; } x; x.i = ((u32)(unsigned short)u) << 16; return x.f;
}
__device__ __forceinline__ short f2b(float f) {
    bf16 h = (bf16)f; return *(short*)&h;
}

// async global->LDS 16B DMA (wave-uniform base + lane*16 pattern)
__device__ __forceinline__ void glds16(const bf16* g, bf16* l) {
#if __has_builtin(__builtin_amdgcn_global_load_lds)
    __builtin_amdgcn_global_load_lds(
        (const __attribute__((address_space(1))) u32*)g,
        (__attribute__((address_space(3))) u32*)l, 16, 0, 0);
#else
    *(uint4*)l = *(const uint4*)g;
#endif
}

// ---- convert fp32 -> bf16 (13 tensors: q,k,v + 10 weights) ----
struct CvtArgs { const float* src[13]; bf16* dst[13]; int n[13]; int bb[14]; };
__global__ __launch_bounds__(256)
void convert_kernel(CvtArgs a) {
    const int blk = blockIdx.x;
    int s = 0;
    while (s < 12 && blk >= a.bb[s + 1]) ++s;
    const int base = (blk - a.bb[s]) * 1024 + threadIdx.x * 4;
    if (base >= a.n[s]) return;            // all n % 4 == 0
    float4 v = *(const float4*)(a.src[s] + base);
    ushort4 o;
    o.x = (unsigned short)f2b(v.x); o.y = (unsigned short)f2b(v.y);
    o.z = (unsigned short)f2b(v.z); o.w = (unsigned short)f2b(v.w);
    *(ushort4*)(a.dst[s] + base) = o;
}

// ---- GEMM tile core: C[M,N] = A[M,K] @ W[N,K]^T + bias ----
// 256 threads = 4 waves (2x2). Wave owns (BM/2)x(BN/2); 16x16x32 MFMA frags.
template<int BM, int BN, bool OUT_F32>
__device__ __forceinline__ void gemm_core(
    const bf16* __restrict__ A, const bf16* __restrict__ W,
    const bf16* __restrict__ bias, void* __restrict__ out,
    int m0, int n0, int N, int K, bf16* lA, bf16* lB) {
    constexpr int WM = BM / 2, WN = BN / 2, FM = WM / 16, FN = WN / 16;
    constexpr int SA = BM / 64, SB = BN / 64;     // glds iters (256 thr x 16B = 64 rows x 32 cols)
    const int tid = threadIdx.x;
    const int wave = tid >> 6, lane = tid & 63;
    const int wr = wave >> 1, wc = wave & 1;
    const int quad = lane >> 4, lm = lane & 15;
    f32x4 acc[FM][FN] = {};
    for (int k0 = 0; k0 < K; k0 += 32) {
#pragma unroll
        for (int q = 0; q < SA; ++q) {
            int sl = q * 256 + tid;
            glds16(A + (size_t)(m0 + (sl >> 2)) * K + k0 + (sl & 3) * 8, lA + sl * 8);
        }
#pragma unroll
        for (int q = 0; q < SB; ++q) {
            int sl = q * 256 + tid;
            glds16(W + (size_t)(n0 + (sl >> 2)) * K + k0 + (sl & 3) * 8, lB + sl * 8);
        }
        __syncthreads();
        s16x8 af[FM], bf_[FN];
#pragma unroll
        for (int i = 0; i < FM; ++i)
            af[i] = *(const s16x8*)&lA[(wr * WM + i * 16 + lm) * 32 + quad * 8];
#pragma unroll
        for (int j = 0; j < FN; ++j)
            bf_[j] = *(const s16x8*)&lB[(wc * WN + j * 16 + lm) * 32 + quad * 8];
#pragma unroll
        for (int i = 0; i < FM; ++i)
#pragma unroll
            for (int j = 0; j < FN; ++j)
                acc[i][j] = __builtin_amdgcn_mfma_f32_16x16x32_bf16(af[i], bf_[j], acc[i][j], 0, 0, 0);
        __syncthreads();
    }
#pragma unroll
    for (int i = 0; i < FM; ++i) {
        const int rbase = m0 + wr * WM + i * 16 + quad * 4;
#pragma unroll
        for (int j = 0; j < FN; ++j) {
            const int col = n0 + wc * WN + j * 16 + lm;
            const float bv = (float)bias[col];
#pragma unroll
            for (int r = 0; r < 4; ++r) {
                float v = acc[i][j][r] + bv;
                size_t off = (size_t)(rbase + r) * N + col;
                if (OUT_F32) ((float*)out)[off] = v;
                else         ((bf16*)out)[off] = (bf16)v;
            }
        }
    }
}

// ---- fused Q/K/V projection: 384 blocks, XCD-swizzled ----
// per XCD: 2 m-tiles(128) x 24 n-tiles (5 Q + 5 K + 14 V)
__global__ __launch_bounds__(256)
void proj_kernel(const bf16* __restrict__ qc, const bf16* __restrict__ kc,
                 const bf16* __restrict__ vc,
                 const bf16* __restrict__ Qkc, const bf16* __restrict__ Kkc,
                 const bf16* __restrict__ Vkc,
                 const bf16* __restrict__ Qbc, const bf16* __restrict__ Kbc,
                 const bf16* __restrict__ Vbc,
                 float* __restrict__ qp, float* __restrict__ kp,
                 bf16* __restrict__ vp) {
    __shared__ __align__(16) bf16 lA[128 * 32];
    __shared__ __align__(16) bf16 lB[128 * 32];
    const int L = blockIdx.x, xcd = L & 7, i = L >> 3;
    const int m0 = (xcd * 2 + i / 24) * 128;
    const int nid = i % 24;
    if (nid < 5)
        gemm_core<128, 128, true >(qc, Qkc, Qbc, qp, m0, nid * 128, 640, 640, lA, lB);
    else if (nid < 10)
        gemm_core<128, 128, true >(kc, Kkc, Kbc, kp, m0, (nid - 5) * 128, 640, 640, lA, lB);
    else
        gemm_core<128, 128, false>(vc, Vkc, Vbc, vp, m0, (nid - 10) * 128, 1792, 640, lA, lB);
}

// ---- collapse GEMM: 160 blocks of 128x64, XCD-swizzled ----
__global__ __launch_bounds__(256)
void collapse_kernel(const bf16* __restrict__ atn, const bf16* __restrict__ Ckc,
                     const bf16* __restrict__ Cbc, float* __restrict__ out) {
    __shared__ __align__(16) bf16 lA[128 * 32];
    __shared__ __align__(16) bf16 lB[64 * 32];
    const int L = blockIdx.x, xcd = L & 7, i = L >> 3;
    const int m0 = (xcd * 2 + i / 10) * 128;
    const int n0 = (i % 10) * 64;
    gemm_core<128, 64, true>(atn, Ckc, Cbc, out, m0, n0, 640, 1792, lA, lB);
}

// ---- attention core: one block per position, XCD-swizzled ----
__global__ __launch_bounds__(256)
void attn_v4(const float* __restrict__ qp, const float* __restrict__ kp,
             const bf16* __restrict__ vp,
             const bf16* __restrict__ Kbc, const bf16* __restrict__ Vbc,
             const bf16* __restrict__ Skc, const bf16* __restrict__ Sbc,
             bf16* __restrict__ atn) {
    const int pos = ((blockIdx.x & 7) << 8) | (blockIdx.x >> 3);  // XCD-contiguous
    const int b = pos >> 10, l = pos & 1023;
    const int t = threadIdx.x;
    __shared__ float qs[640];
    __shared__ float sc5[5 * 32];
    __shared__ float sc14[14 * 32];
    __shared__ float w14T[32 * 14];   // transposed: [tap][head]

    if (t < 160) ((float4*)qs)[t] = ((const float4*)(qp + (size_t)pos * 640))[t];
    __syncthreads();

    // Phase A: score[s][j] = q[s].kwin[s][j]; 8 lanes/dot, stride-32 interleave
    // (qs banks = p*4+{0..3} -> conflict-free), shfl_xor reduce over the 8 lanes.
    {
        const int j = t >> 3, p = t & 7;
#pragma unroll
        for (int s = 0; s < 5; ++s) {
            const int dil = (s < 2) ? 1 : (1 << (s - 1));
            const int pl = (31 * dil) >> 1;
            const int row = l + j * dil - pl;
            const float* q = qs + s * 128 + p * 4;
            float acc = 0.f;
            if (row >= 0 && row < 1024) {
                const float* kr = kp + (size_t)((b << 10) | row) * 640 + s * 128 + p * 4;
#pragma unroll
                for (int g = 0; g < 4; ++g) {
                    float4 kv = *(const float4*)(kr + g * 32);
                    float4 qv = *(const float4*)(q + g * 32);
                    acc += qv.x * kv.x + qv.y * kv.y + qv.z * kv.z + qv.w * kv.w;
                }
            } else {
                const bf16* kb = Kbc + s * 128 + p * 4;   // pad rows project the bias
#pragma unroll
                for (int g = 0; g < 4; ++g) {
                    float4 qv = *(const float4*)(q + g * 32);
                    acc += qv.x * (float)kb[g * 32] + qv.y * (float)kb[g * 32 + 1]
                         + qv.z * (float)kb[g * 32 + 2] + qv.w * (float)kb[g * 32 + 3];
                }
            }
            acc += __shfl_xor(acc, 1);
            acc += __shfl_xor(acc, 2);
            acc += __shfl_xor(acc, 4);
            if (p == 0) sc5[s * 32 + j] = acc;
        }
    }
    __syncthreads();

    // Phase B: supersample + positional resampling (448 outputs), vectorized Sk
    for (int idx = t; idx < 448; idx += 256) {
        const int h = idx >> 5;
        const int s = (h < 5) ? 0 : (h < 10) ? 1 : (h < 12) ? 2 : (h == 12) ? 3 : 4;
        const s16x8* sk = (const s16x8*)((const short*)Skc + idx * 32);
        const float* sc = sc5 + s * 32;
        float acc = b2f(((const short*)Sbc)[idx]);
#pragma unroll
        for (int g = 0; g < 4; ++g) {
            s16x8 kk = sk[g];
#pragma unroll
            for (int r = 0; r < 8; ++r) acc += sc[g * 8 + r] * b2f(kk[r]);
        }
        sc14[idx] = acc;
    }
    __syncthreads();

    // Phase C: softmax, 16 lanes/head (2 taps each), shuffle-reduce width 16
    if (t < 224) {
        const int h = t >> 4, u = t & 15;
        float s0 = sc14[h * 32 + u], s1 = sc14[h * 32 + u + 16];
        float mx = fmaxf(s0, s1);
#pragma unroll
        for (int m = 1; m < 16; m <<= 1) mx = fmaxf(mx, __shfl_xor(mx, m));
        float e0 = __expf(s0 - mx), e1 = __expf(s1 - mx);
        float sum = e0 + e1;
#pragma unroll
        for (int m = 1; m < 16; m <<= 1) sum += __shfl_xor(sum, m);
        float inv = 1.f / sum;
        w14T[u * 14 + h] = e0 * inv;
        w14T[(u + 16) * 14 + h] = e1 * inv;
    }
    __syncthreads();

    // Phase D: attn[h][d8] = sum_j w[j][h] * vwin[h][j][d8]; conflict-free w reads
    if (t < 224) {
        const int h = t >> 4, d8 = (t & 15) * 8;
        const int dil = (h < 10) ? 1 : (h < 12) ? 2 : (h == 12) ? 4 : 8;
        const int pl = (31 * dil) >> 1;
        const int col = h * 128 + d8;
        float acc[8] = {};
#pragma unroll
        for (int j = 0; j < 32; ++j) {
            const int row = l + j * dil - pl;
            const short* src = (row >= 0 && row < 1024)
                ? (const short*)vp + (size_t)((b << 10) | row) * 1792 + col
                : (const short*)Vbc + col;     // pad rows project the bias
            s16x8 v8 = *(const s16x8*)src;
            const float w = w14T[j * 14 + h];
#pragma unroll
            for (int r = 0; r < 8; ++r) acc[r] += w * b2f(v8[r]);
        }
        union { uint4 u; short h16[8]; } o;
#pragma unroll
        for (int r = 0; r < 8; ++r) o.h16[r] = f2b(acc[r]);
        *(uint4*)((short*)atn + (size_t)pos * 1792 + col) = o.u;
    }
}

extern "C" void kernel_launch(void* const* d_in, const int* in_sizes, int n_in,
                              void* d_out, int out_size, void* d_ws, size_t ws_size,
                              hipStream_t stream) {
    const int M = 2048;
    char* w = (char*)d_ws;
    size_t off = 0;
    auto alloc = [&](size_t bytes) -> char* {
        off = (off + 255) & ~(size_t)255;
        char* p = w + off; off += bytes; return p;
    };
    bf16* qc  = (bf16*)alloc(1310720 * 2);
    bf16* kc  = (bf16*)alloc(1310720 * 2);
    bf16* vc  = (bf16*)alloc(1310720 * 2);
    bf16* Qkc = (bf16*)alloc(409600 * 2);
    bf16* Qbc = (bf16*)alloc(640 * 2);
    bf16* Kkc = (bf16*)alloc(409600 * 2);
    bf16* Kbc = (bf16*)alloc(640 * 2);
    bf16* Vkc = (bf16*)alloc(1146880 * 2);
    bf16* Vbc = (bf16*)alloc(1792 * 2);
    bf16* Skc = (bf16*)alloc(14336 * 2);
    bf16* Sbc = (bf16*)alloc(448 * 2);
    bf16* Ckc = (bf16*)alloc(1146880 * 2);
    bf16* Cbc = (bf16*)alloc(640 * 2);
    float* qp = (float*)alloc((size_t)M * 640 * 4);
    float* kp = (float*)alloc((size_t)M * 640 * 4);
    bf16*  vp = (bf16*)alloc((size_t)M * 1792 * 2);
    bf16*  atn = (bf16*)alloc((size_t)M * 1792 * 2);

    CvtArgs ca;
    bf16* dsts[13] = {qc, kc, vc, Qkc, Qbc, Kkc, Kbc, Vkc, Vbc, Skc, Sbc, Ckc, Cbc};
    const int ns[13] = {1310720, 1310720, 1310720, 409600, 640, 409600, 640,
                        1146880, 1792, 14336, 448, 1146880, 640};
    int cum = 0;
    for (int i = 0; i < 13; ++i) {
        ca.src[i] = (const float*)d_in[i];
        ca.dst[i] = dsts[i];
        ca.n[i] = ns[i];
        ca.bb[i] = cum;
        cum += (ns[i] + 1023) / 1024;
    }
    ca.bb[13] = cum;

    dim3 blk(256);
    convert_kernel<<<dim3(cum), blk, 0, stream>>>(ca);
    proj_kernel<<<dim3(384), blk, 0, stream>>>(qc, kc, vc, Qkc, Kkc, Vkc,
                                               Qbc, Kbc, Vbc, qp, kp, vp);
    attn_v4<<<dim3(2048), blk, 0, stream>>>(qp, kp, vp, Kbc, Vbc, Skc, Sbc, atn);
    collapse_kernel<<<dim3(160), blk, 0, stream>>>(atn, Ckc, Cbc, (float*)d_out);
}

// Round 6
// 166.486 us; speedup vs baseline: 2.4076x; 1.0306x over previous
//
#include <hip/hip_runtime.h>
#include <hip/hip_bf16.h>

using bf16 = __hip_bfloat16;
typedef __attribute__((ext_vector_type(8))) short s16x8;
typedef __attribute__((ext_vector_type(4))) float f32x4;
typedef unsigned int u32;

__device__ __forceinline__ float b2f(short u) {
    union { float f; u32 i; } x; x.i = ((u32)(unsigned short)u) << 16; return x.f;
}
__device__ __forceinline__ short f2b(float f) {
    bf16 h = (bf16)f; return *(short*)&h;
}

// ---- convert weights fp32 -> bf16 (10 tensors) ----
struct CvtArgs { const float* src[10]; bf16* dst[10]; int n[10]; int bb[11]; };
__global__ __launch_bounds__(256)
void convert_kernel(CvtArgs a) {
    const int blk = blockIdx.x;
    int s = 0;
    while (s < 9 && blk >= a.bb[s + 1]) ++s;
    const int base = (blk - a.bb[s]) * 1024 + threadIdx.x * 4;
    if (base >= a.n[s]) return;            // all n % 4 == 0
    float4 v = *(const float4*)(a.src[s] + base);
    ushort4 o;
    o.x = (unsigned short)f2b(v.x); o.y = (unsigned short)f2b(v.y);
    o.z = (unsigned short)f2b(v.z); o.w = (unsigned short)f2b(v.w);
    *(ushort4*)(a.dst[s] + base) = o;
}

// ---- register-pipelined GEMM core: C[M,N] = A[M,K] @ W[N,K]^T + bias ----
// 256 threads = 4 waves (2x2). Global->VGPR staging for tile k+1 is issued
// right after the barrier and overlaps ds_read+MFMA of tile k (latency hidden
// even at 1-2 blocks/CU, where the glds16+barrier structure serializes).
// A either fp32 (convert-on-stage) or bf16.
template<int BM, int BN, bool A_F32, bool OUT_F32>
__device__ __forceinline__ void gemm_pipe(
    const void* __restrict__ A, const bf16* __restrict__ W,
    const bf16* __restrict__ bias, void* __restrict__ out,
    int m0, int n0, int N, int K, bf16* lA, bf16* lB) {
    constexpr int WM = BM / 2, WN = BN / 2, FM = WM / 16, FN = WN / 16;
    constexpr int SA = BM / 64, SB = BN / 64;   // 16B reg slots per thread
    const int tid = threadIdx.x;
    const int wave = tid >> 6, lane = tid & 63;
    const int wr = wave >> 1, wc = wave & 1;
    const int quad = lane >> 4, lm = lane & 15;
    uint4 ra[SA], rb[SB];

    auto loadA = [&](int k0) {
#pragma unroll
        for (int q = 0; q < SA; ++q) {
            const int sl = q * 256 + tid, row = sl >> 2, col = (sl & 3) * 8;
            if (A_F32) {
                const float* g = (const float*)A + (size_t)(m0 + row) * K + k0 + col;
                float4 f0 = *(const float4*)g;
                float4 f1 = *(const float4*)(g + 4);
                union { uint4 u; short h[8]; } p;
                p.h[0] = f2b(f0.x); p.h[1] = f2b(f0.y); p.h[2] = f2b(f0.z); p.h[3] = f2b(f0.w);
                p.h[4] = f2b(f1.x); p.h[5] = f2b(f1.y); p.h[6] = f2b(f1.z); p.h[7] = f2b(f1.w);
                ra[q] = p.u;
            } else {
                ra[q] = *(const uint4*)((const bf16*)A + (size_t)(m0 + row) * K + k0 + col);
            }
        }
    };
    auto loadB = [&](int k0) {
#pragma unroll
        for (int q = 0; q < SB; ++q) {
            const int sl = q * 256 + tid, row = sl >> 2, col = (sl & 3) * 8;
            rb[q] = *(const uint4*)(W + (size_t)(n0 + row) * K + k0 + col);
        }
    };

    f32x4 acc[FM][FN] = {};
    loadA(0); loadB(0);
    for (int k0 = 0; k0 < K; k0 += 32) {
#pragma unroll
        for (int q = 0; q < SA; ++q) *(uint4*)(lA + (q * 256 + tid) * 8) = ra[q];
#pragma unroll
        for (int q = 0; q < SB; ++q) *(uint4*)(lB + (q * 256 + tid) * 8) = rb[q];
        __syncthreads();
        if (k0 + 32 < K) { loadA(k0 + 32); loadB(k0 + 32); }   // overlaps MFMA below
        s16x8 af[FM], bf_[FN];
#pragma unroll
        for (int i = 0; i < FM; ++i)
            af[i] = *(const s16x8*)&lA[(wr * WM + i * 16 + lm) * 32 + quad * 8];
#pragma unroll
        for (int j = 0; j < FN; ++j)
            bf_[j] = *(const s16x8*)&lB[(wc * WN + j * 16 + lm) * 32 + quad * 8];
#pragma unroll
        for (int i = 0; i < FM; ++i)
#pragma unroll
            for (int j = 0; j < FN; ++j)
                acc[i][j] = __builtin_amdgcn_mfma_f32_16x16x32_bf16(af[i], bf_[j], acc[i][j], 0, 0, 0);
        __syncthreads();
    }
#pragma unroll
    for (int i = 0; i < FM; ++i) {
        const int rbase = m0 + wr * WM + i * 16 + quad * 4;
#pragma unroll
        for (int j = 0; j < FN; ++j) {
            const int col = n0 + wc * WN + j * 16 + lm;
            const float bv = (float)bias[col];
#pragma unroll
            for (int r = 0; r < 4; ++r) {
                float v = acc[i][j][r] + bv;
                size_t off = (size_t)(rbase + r) * N + col;
                if (OUT_F32) ((float*)out)[off] = v;
                else         ((bf16*)out)[off] = (bf16)v;
            }
        }
    }
}

// ---- fused Q/K/V projection: 768 blocks (3/CU), 128x64 tiles, XCD-swizzled ----
// per XCD: 2 m-tiles(128) x 48 n-tiles (10 Q + 10 K + 28 V of width 64)
__global__ __launch_bounds__(256)
void proj_kernel(const float* __restrict__ q, const float* __restrict__ k,
                 const float* __restrict__ v,
                 const bf16* __restrict__ Qkc, const bf16* __restrict__ Kkc,
                 const bf16* __restrict__ Vkc,
                 const bf16* __restrict__ Qbc, const bf16* __restrict__ Kbc,
                 const bf16* __restrict__ Vbc,
                 float* __restrict__ qp, float* __restrict__ kp,
                 bf16* __restrict__ vp) {
    __shared__ __align__(16) bf16 lA[128 * 32];
    __shared__ __align__(16) bf16 lB[64 * 32];
    const int L = blockIdx.x, xcd = L & 7, i = L >> 3;
    const int m0 = (xcd * 2 + i / 48) * 128;
    const int nid = i % 48;
    if (nid < 10)
        gemm_pipe<128, 64, true, true >(q, Qkc, Qbc, qp, m0, nid * 64, 640, 640, lA, lB);
    else if (nid < 20)
        gemm_pipe<128, 64, true, true >(k, Kkc, Kbc, kp, m0, (nid - 10) * 64, 640, 640, lA, lB);
    else
        gemm_pipe<128, 64, true, false>(v, Vkc, Vbc, vp, m0, (nid - 20) * 64, 1792, 640, lA, lB);
}

// ---- collapse GEMM: 320 blocks (1.25/CU) of 64x64, K=1792, XCD-swizzled ----
__global__ __launch_bounds__(256)
void collapse_kernel(const bf16* __restrict__ atn, const bf16* __restrict__ Ckc,
                     const bf16* __restrict__ Cbc, float* __restrict__ out) {
    __shared__ __align__(16) bf16 lA[64 * 32];
    __shared__ __align__(16) bf16 lB[64 * 32];
    const int L = blockIdx.x, xcd = L & 7, i = L >> 3;
    const int m0 = (xcd * 4 + i / 10) * 64;
    const int n0 = (i % 10) * 64;
    gemm_pipe<64, 64, false, true>(atn, Ckc, Cbc, out, m0, n0, 640, 1792, lA, lB);
}

// ---- attention core: one block per position, XCD-swizzled (as R5) ----
__global__ __launch_bounds__(256)
void attn_v4(const float* __restrict__ qp, const float* __restrict__ kp,
             const bf16* __restrict__ vp,
             const bf16* __restrict__ Kbc, const bf16* __restrict__ Vbc,
             const bf16* __restrict__ Skc, const bf16* __restrict__ Sbc,
             bf16* __restrict__ atn) {
    const int pos = ((blockIdx.x & 7) << 8) | (blockIdx.x >> 3);  // XCD-contiguous
    const int b = pos >> 10, l = pos & 1023;
    const int t = threadIdx.x;
    __shared__ float qs[640];
    __shared__ float sc5[5 * 32];
    __shared__ float sc14[14 * 32];
    __shared__ float w14T[32 * 14];   // transposed: [tap][head]

    if (t < 160) ((float4*)qs)[t] = ((const float4*)(qp + (size_t)pos * 640))[t];
    __syncthreads();

    // Phase A: score[s][j] = q[s].kwin[s][j]; 8 lanes/dot, stride-32 interleave
    {
        const int j = t >> 3, p = t & 7;
#pragma unroll
        for (int s = 0; s < 5; ++s) {
            const int dil = (s < 2) ? 1 : (1 << (s - 1));
            const int pl = (31 * dil) >> 1;
            const int row = l + j * dil - pl;
            const float* q = qs + s * 128 + p * 4;
            float acc = 0.f;
            if (row >= 0 && row < 1024) {
                const float* kr = kp + (size_t)((b << 10) | row) * 640 + s * 128 + p * 4;
#pragma unroll
                for (int g = 0; g < 4; ++g) {
                    float4 kv = *(const float4*)(kr + g * 32);
                    float4 qv = *(const float4*)(q + g * 32);
                    acc += qv.x * kv.x + qv.y * kv.y + qv.z * kv.z + qv.w * kv.w;
                }
            } else {
                const bf16* kb = Kbc + s * 128 + p * 4;   // pad rows project the bias
#pragma unroll
                for (int g = 0; g < 4; ++g) {
                    float4 qv = *(const float4*)(q + g * 32);
                    acc += qv.x * (float)kb[g * 32] + qv.y * (float)kb[g * 32 + 1]
                         + qv.z * (float)kb[g * 32 + 2] + qv.w * (float)kb[g * 32 + 3];
                }
            }
            acc += __shfl_xor(acc, 1);
            acc += __shfl_xor(acc, 2);
            acc += __shfl_xor(acc, 4);
            if (p == 0) sc5[s * 32 + j] = acc;
        }
    }
    __syncthreads();

    // Phase B: supersample + positional resampling (448 outputs), vectorized Sk
    for (int idx = t; idx < 448; idx += 256) {
        const int h = idx >> 5;
        const int s = (h < 5) ? 0 : (h < 10) ? 1 : (h < 12) ? 2 : (h == 12) ? 3 : 4;
        const s16x8* sk = (const s16x8*)((const short*)Skc + idx * 32);
        const float* sc = sc5 + s * 32;
        float acc = b2f(((const short*)Sbc)[idx]);
#pragma unroll
        for (int g = 0; g < 4; ++g) {
            s16x8 kk = sk[g];
#pragma unroll
            for (int r = 0; r < 8; ++r) acc += sc[g * 8 + r] * b2f(kk[r]);
        }
        sc14[idx] = acc;
    }
    __syncthreads();

    // Phase C: softmax, 16 lanes/head (2 taps each), shuffle-reduce width 16
    if (t < 224) {
        const int h = t >> 4, u = t & 15;
        float s0 = sc14[h * 32 + u], s1 = sc14[h * 32 + u + 16];
        float mx = fmaxf(s0, s1);
#pragma unroll
        for (int m = 1; m < 16; m <<= 1) mx = fmaxf(mx, __shfl_xor(mx, m));
        float e0 = __expf(s0 - mx), e1 = __expf(s1 - mx);
        float sum = e0 + e1;
#pragma unroll
        for (int m = 1; m < 16; m <<= 1) sum += __shfl_xor(sum, m);
        float inv = 1.f / sum;
        w14T[u * 14 + h] = e0 * inv;
        w14T[(u + 16) * 14 + h] = e1 * inv;
    }
    __syncthreads();

    // Phase D: attn[h][d8] = sum_j w[j][h] * vwin[h][j][d8]
    if (t < 224) {
        const int h = t >> 4, d8 = (t & 15) * 8;
        const int dil = (h < 10) ? 1 : (h < 12) ? 2 : (h == 12) ? 4 : 8;
        const int pl = (31 * dil) >> 1;
        const int col = h * 128 + d8;
        float acc[8] = {};
#pragma unroll
        for (int j = 0; j < 32; ++j) {
            const int row = l + j * dil - pl;
            const short* src = (row >= 0 && row < 1024)
                ? (const short*)vp + (size_t)((b << 10) | row) * 1792 + col
                : (const short*)Vbc + col;     // pad rows project the bias
            s16x8 v8 = *(const s16x8*)src;
            const float w = w14T[j * 14 + h];
#pragma unroll
            for (int r = 0; r < 8; ++r) acc[r] += w * b2f(v8[r]);
        }
        union { uint4 u; short h16[8]; } o;
#pragma unroll
        for (int r = 0; r < 8; ++r) o.h16[r] = f2b(acc[r]);
        *(uint4*)((short*)atn + (size_t)pos * 1792 + col) = o.u;
    }
}

extern "C" void kernel_launch(void* const* d_in, const int* in_sizes, int n_in,
                              void* d_out, int out_size, void* d_ws, size_t ws_size,
                              hipStream_t stream) {
    const int M = 2048;
    char* w = (char*)d_ws;
    size_t off = 0;
    auto alloc = [&](size_t bytes) -> char* {
        off = (off + 255) & ~(size_t)255;
        char* p = w + off; off += bytes; return p;
    };
    bf16* Qkc = (bf16*)alloc(409600 * 2);
    bf16* Qbc = (bf16*)alloc(640 * 2);
    bf16* Kkc = (bf16*)alloc(409600 * 2);
    bf16* Kbc = (bf16*)alloc(640 * 2);
    bf16* Vkc = (bf16*)alloc(1146880 * 2);
    bf16* Vbc = (bf16*)alloc(1792 * 2);
    bf16* Skc = (bf16*)alloc(14336 * 2);
    bf16* Sbc = (bf16*)alloc(448 * 2);
    bf16* Ckc = (bf16*)alloc(1146880 * 2);
    bf16* Cbc = (bf16*)alloc(640 * 2);
    float* qp = (float*)alloc((size_t)M * 640 * 4);
    float* kp = (float*)alloc((size_t)M * 640 * 4);
    bf16*  vp = (bf16*)alloc((size_t)M * 1792 * 2);
    bf16*  atn = (bf16*)alloc((size_t)M * 1792 * 2);

    CvtArgs ca;
    bf16* dsts[10] = {Qkc, Qbc, Kkc, Kbc, Vkc, Vbc, Skc, Sbc, Ckc, Cbc};
    const int ns[10] = {409600, 640, 409600, 640, 1146880, 1792, 14336, 448, 1146880, 640};
    int cum = 0;
    for (int i = 0; i < 10; ++i) {
        ca.src[i] = (const float*)d_in[3 + i];
        ca.dst[i] = dsts[i];
        ca.n[i] = ns[i];
        ca.bb[i] = cum;
        cum += (ns[i] + 1023) / 1024;
    }
    ca.bb[10] = cum;

    dim3 blk(256);
    convert_kernel<<<dim3(cum), blk, 0, stream>>>(ca);
    proj_kernel<<<dim3(768), blk, 0, stream>>>(
        (const float*)d_in[0], (const float*)d_in[1], (const float*)d_in[2],
        Qkc, Kkc, Vkc, Qbc, Kbc, Vbc, qp, kp, vp);
    attn_v4<<<dim3(2048), blk, 0, stream>>>(qp, kp, vp, Kbc, Vbc, Skc, Sbc, atn);
    collapse_kernel<<<dim3(320), blk, 0, stream>>>(atn, Ckc, Cbc, (float*)d_out);
}